// Round 3
// baseline (448.465 us; speedup 1.0000x reference)
//
#include <hip/hip_runtime.h>

// MultiRelGraphTransformer on MI355X — round 9.
// vs r8: k_spmm is restructured for L2 residency, not instruction scheduling
// (r6/r7/r8 all landed 62±4µs — inner-loop rearrangement is not the constraint):
// (a) column-half split mapped to XCDs: 8 tasks = (batch, col-half), hot gather
//     set per XCD = 20000 x 128B = 2.56MB < 4MB L2 (was 5.1MB, thrashing),
//     8B/lane dwordx2 gathers, same summation tree (absmax bit-identical);
// (b) non-temporal stores for G (70MB write-allocate was evicting the hot set)
//     and nt loads for streamed srcs; HB gather loads stay cacheable;
// (c) k_gemm_ln: nt loads on read-once G staging; otherwise unchanged (r6 shape).

#define NNODES 20000
#define NB     4
#define BROWS  (NB * NNODES)   // 80000
#define DN     64
#define DM     128
#define NE     160000
#define CAP    64              // bucket capacity per (relation,dst); Poisson(8)
#define LN_EPS 1e-5f
#define KE     448             // 384 spmm cols + 64 ext cols
#define LDW    88              // LDS row stride in ushorts: 44 dw -> 2-way (free)

typedef __attribute__((ext_vector_type(8))) short bf16x8;
typedef __attribute__((ext_vector_type(4))) float f32x4;
typedef __attribute__((ext_vector_type(2))) float f32x2;
typedef __attribute__((ext_vector_type(8))) unsigned short u16x8;
typedef __attribute__((ext_vector_type(4))) unsigned short u16x4;
typedef __attribute__((ext_vector_type(4))) int i32x4;
typedef __attribute__((ext_vector_type(2))) unsigned int u32x2;
typedef __attribute__((ext_vector_type(4))) unsigned int u32x4;

__device__ inline float bf2f(unsigned short u) {
    union { unsigned int i; float f; } x; x.i = ((unsigned int)u) << 16; return x.f;
}
__device__ inline unsigned short f2bf(float f) {
    union { float f; unsigned int i; } x; x.f = f;
    unsigned int r = x.i + 0x7FFFu + ((x.i >> 16) & 1u);
    return (unsigned short)(r >> 16);
}
// unpack one dword (2 bf16) into a packed float2 {lo, hi}
__device__ inline f32x2 bfpair(unsigned int w) {
    union { unsigned int u; float f; } lo, hi;
    lo.u = w << 16; hi.u = w & 0xffff0000u;
    return (f32x2){lo.f, hi.f};
}

// ---------- K1: counting-sort into fixed buckets (cursor = true degree) ----------
// srcs[] stores BYTE offsets into an HB batch plane: src * DM * 2 = src*256.
__global__ void k_scatter(const int* __restrict__ ei0, const int* __restrict__ ei1,
                          const int* __restrict__ ei2, int* __restrict__ cursor,
                          int* __restrict__ srcs, int* __restrict__ eids) {
    int tid = blockIdx.x * blockDim.x + threadIdx.x;
    if (tid >= 3 * NE) return;
    int r = tid / NE, e = tid - r * NE;
    const int* ei = (r == 0) ? ei0 : ((r == 1) ? ei1 : ei2);
    int src = ei[e], dst = ei[NE + e];
    int p = atomicAdd(&cursor[r * NNODES + dst], 1);
    if (p < CAP) {
        srcs[(r * NNODES + dst) * CAP + p] = src << 8;   // byte offset
        if (r < 2) eids[(r * NNODES + dst) * CAP + p] = e;
    }
}

// ---------- K2: S[r][n][16] = sum of ea_r over incoming edges (bucket walk) ----------
__global__ __launch_bounds__(256) void k_sgather(const int* __restrict__ deg,
                                                 const int* __restrict__ eids,
                                                 const float* __restrict__ ea0,
                                                 const float* __restrict__ ea1,
                                                 float* __restrict__ S) {
    int task = blockIdx.x * 4 + (threadIdx.x >> 6);   // 0 .. 2*NNODES-1
    int r = task / NNODES;
    const float* ea = r ? ea1 : ea0;
    int lane = threadIdx.x & 63;
    int k = lane & 15, sub = lane >> 4;
    int dg = deg[task]; if (dg > CAP) dg = CAP;
    const int* bk = eids + (size_t)task * CAP;
    float acc = 0.f;
    for (int j = sub; j < dg; j += 4) {
        int e = bk[j];
        acc += ea[e * 16 + k];
    }
    acc += __shfl_xor(acc, 16, 64);
    acc += __shfl_xor(acc, 32, 64);
    if (lane < 16) S[(size_t)task * 16 + k] = acc;
}

// ---------- K3: build Wt[2][128][448] (transposed node_W + ext rows) and Wp[128][64] ----------
__global__ __launch_bounds__(256) void k_wprep(const float* __restrict__ nW,
                                               const float* __restrict__ nb,
                                               const float* __restrict__ eW,
                                               const float* __restrict__ eb,
                                               const float* __restrict__ inW,
                                               unsigned short* __restrict__ Wt,
                                               unsigned short* __restrict__ Wp) {
    int lin = blockIdx.x * 256 + threadIdx.x;    // 2*128*448 + 128*64 = 122880
    if (lin < 2 * 128 * KE) {
        int l = lin / (128 * KE);
        int rem = lin - l * 128 * KE;
        int n = rem / KE, k = rem - n * KE;
        float v;
        if (k < 384) {
            int r = k >> 7, kk = k & 127;
            v = nW[(((size_t)(l * 3 + r) * 128) + kk) * 128 + n];
        } else {
            int e = k - 384;
            if (e < 3) {
                v = nb[(l * 3 + e) * DM + n];
                if (e < 2) v += eb[(l * 2 + e) * DM + n];
            } else if (e < 35) {
                int r2 = (e - 3) >> 4, j = (e - 3) & 15;
                v = eW[((size_t)((l * 2 + r2) * 16 + j)) * DM + n];
            } else v = 0.f;
        }
        Wt[lin] = f2bf(v);
    } else {
        int i = lin - 2 * 128 * KE;
        int n = i >> 6, k = i & 63;
        Wp[n * 64 + k] = f2bf(inW[(size_t)k * DM + n]);
    }
}

// ---------- K4: input projection HB = bf16(node_feat @ in_W + in_b), MFMA ----------
__global__ __launch_bounds__(256) void k_proj(const float* __restrict__ X,
                                              const unsigned short* __restrict__ Wp,  // [128][64]
                                              const float* __restrict__ bias,
                                              unsigned short* __restrict__ HB) {
    __shared__ __align__(16) unsigned short As[64][LDW];
    __shared__ __align__(16) unsigned short Bs[128][LDW];
    int t = threadIdx.x;
    int m0 = blockIdx.x * 64;
#pragma unroll
    for (int i = 0; i < 4; ++i) {
        int lin = t + 256 * i;                 // 0..1023 (64 rows x 16 float4-segs)
        int row = lin >> 4, seg = lin & 15;
        float4 v = *(const float4*)(X + (size_t)(m0 + row) * DN + seg * 4);
        ushort4 h; h.x = f2bf(v.x); h.y = f2bf(v.y); h.z = f2bf(v.z); h.w = f2bf(v.w);
        *(ushort4*)&As[row][seg * 4] = h;
    }
#pragma unroll
    for (int i = 0; i < 4; ++i) {
        int lin = t + 256 * i;                 // 0..1023 (128 rows x 8 uint4-segs)
        int row = lin >> 3, seg = lin & 7;
        *(uint4*)&Bs[row][seg * 8] = *(const uint4*)(Wp + (size_t)row * 64 + seg * 8);
    }
    __syncthreads();
    int w = t >> 6, lane = t & 63;
    int q = lane >> 4, lm = lane & 15;
    f32x4 acc[8];
#pragma unroll
    for (int ct = 0; ct < 8; ++ct) acc[ct] = (f32x4){0.f, 0.f, 0.f, 0.f};
#pragma unroll
    for (int kt = 0; kt < 2; ++kt) {
        bf16x8 a = *(const bf16x8*)&As[w * 16 + lm][kt * 32 + q * 8];
#pragma unroll
        for (int ct = 0; ct < 8; ++ct) {
            bf16x8 bf = *(const bf16x8*)&Bs[ct * 16 + lm][kt * 32 + q * 8];
            acc[ct] = __builtin_amdgcn_mfma_f32_16x16x32_bf16(a, bf, acc[ct], 0, 0, 0);
        }
    }
#pragma unroll
    for (int reg = 0; reg < 4; ++reg) {
        int row = m0 + w * 16 + q * 4 + reg;
#pragma unroll
        for (int ct = 0; ct < 8; ++ct) {
            int col = ct * 16 + lm;
            HB[(size_t)row * DM + col] = f2bf(acc[ct][reg] + bias[col]);
        }
    }
}

// ---------- gather one relation, one column half: 8B/lane, idx-pipelined ----------
__device__ inline void gather_rel_h(const char* __restrict__ HbB2, unsigned c8,
                                    const int* __restrict__ bk, int dg, f32x2* a) {
    a[0] = (f32x2){0.f, 0.f};
    a[1] = (f32x2){0.f, 0.f};
    int j = 0;
    if (dg >= 4) {
        i32x4 s4 = __builtin_nontemporal_load((const i32x4*)bk);
        while (j + 3 < dg) {
            i32x4 nxt = s4;
            if (j + 7 < dg) nxt = __builtin_nontemporal_load((const i32x4*)(bk + j + 4));
            u32x2 u0 = *(const u32x2*)(HbB2 + ((unsigned)s4.x + c8));
            u32x2 u1 = *(const u32x2*)(HbB2 + ((unsigned)s4.y + c8));
            u32x2 u2 = *(const u32x2*)(HbB2 + ((unsigned)s4.z + c8));
            u32x2 u3 = *(const u32x2*)(HbB2 + ((unsigned)s4.w + c8));
            a[0] += (bfpair(u0.x) + bfpair(u1.x)) + (bfpair(u2.x) + bfpair(u3.x));
            a[1] += (bfpair(u0.y) + bfpair(u1.y)) + (bfpair(u2.y) + bfpair(u3.y));
            j += 4;
            s4 = nxt;
        }
    }
    for (; j < dg; ++j) {
        u32x2 u = *(const u32x2*)(HbB2 + ((unsigned)bk[j] + c8));
        a[0] += bfpair(u.x);
        a[1] += bfpair(u.y);
    }
}

// ---------- K5: SpMM + ext-col write, (batch, col-half) per XCD ----------
// Block = 16 nodes x one (batch bb, half hh); 16 lanes x dwordx2 per half-row.
// Hot gather set per XCD = 20000 x 128B = 2.56MB -> fits 4MB L2.
__global__ __launch_bounds__(256) void k_spmm(const unsigned short* __restrict__ HB,
                                              const int* __restrict__ deg,
                                              const int* __restrict__ srcs,
                                              const float* __restrict__ S,
                                              unsigned short* __restrict__ G) {
    int blk = blockIdx.x;                      // 10000
    int s = blk & 7;                           // XCD id (round-robin dispatch)
    int bb = s >> 1;                           // batch
    int hh = s & 1;                            // column half
    int idx = blk >> 3;                        // [0,1250)
    int n0 = idx * 16;
    int g = threadIdx.x >> 4, lane = threadIdx.x & 15;
    int n = n0 + g;
    unsigned c8 = (unsigned)lane * 8;          // byte offset within half-row
    const char* HbB2 = (const char*)HB + (size_t)bb * NNODES * DM * 2 + hh * 128;
    size_t rowbase = ((size_t)(bb * NNODES + n)) * KE;

    int dt0 = deg[n], dt1 = deg[NNODES + n], dt2 = deg[2 * NNODES + n];
    const int* bk0 = srcs + (size_t)n * CAP;
    const int* bk1 = bk0 + (size_t)NNODES * CAP;
    const int* bk2 = bk1 + (size_t)NNODES * CAP;

    f32x2 a[2];
    u16x4 o;

    gather_rel_h(HbB2, c8, bk0, dt0 > CAP ? CAP : dt0, a);
    o[0] = f2bf(a[0].x); o[1] = f2bf(a[0].y); o[2] = f2bf(a[1].x); o[3] = f2bf(a[1].y);
    __builtin_nontemporal_store(o, (u16x4*)(G + rowbase + 0 * 128 + hh * 64 + lane * 4));

    gather_rel_h(HbB2, c8, bk1, dt1 > CAP ? CAP : dt1, a);
    o[0] = f2bf(a[0].x); o[1] = f2bf(a[0].y); o[2] = f2bf(a[1].x); o[3] = f2bf(a[1].y);
    __builtin_nontemporal_store(o, (u16x4*)(G + rowbase + 1 * 128 + hh * 64 + lane * 4));

    gather_rel_h(HbB2, c8, bk2, dt2 > CAP ? CAP : dt2, a);
    o[0] = f2bf(a[0].x); o[1] = f2bf(a[0].y); o[2] = f2bf(a[1].x); o[3] = f2bf(a[1].y);
    __builtin_nontemporal_store(o, (u16x4*)(G + rowbase + 2 * 128 + hh * 64 + lane * 4));

    // ext cols: written once (half 0); lanes 0..7 write 8 bf16 each -> kk = lane*8+j
    if (hh == 0 && lane < 8) {
        int dt[3] = {dt0, dt1, dt2};
        u16x8 e;
#pragma unroll
        for (int j = 0; j < 8; ++j) {
            int kk = lane * 8 + j;
            float v;
            if (kk < 3)       v = (float)dt[kk];
            else if (kk < 19) v = S[((size_t)(0 * NNODES + n)) * 16 + (kk - 3)];
            else if (kk < 35) v = S[((size_t)(1 * NNODES + n)) * 16 + (kk - 19)];
            else              v = 0.f;
            e[j] = f2bf(v);
        }
        __builtin_nontemporal_store(e, (u16x8*)(G + rowbase + 384 + lane * 8));
    }
}

// ---------- K6: bf16 MFMA GEMM [64x448]@[448x128] + residual + ReLU + LN ----------
// (r6 shape: 64-row M-tile, 4 blocks/CU, 1250 blocks; nt loads on read-once G)
__global__ __launch_bounds__(256) void k_gemm_ln(const unsigned short* __restrict__ G,   // [BROWS][448]
                                                 const unsigned short* __restrict__ Wt,  // [128][448]
                                                 unsigned short* HB,
                                                 const float* __restrict__ lng,
                                                 const float* __restrict__ lnb,
                                                 float* __restrict__ out, int write_f32) {
    __shared__ __align__(16) unsigned short Gs[64][LDW];
    __shared__ __align__(16) unsigned short Ws[128][LDW];
    int t = threadIdx.x;
    int m0 = blockIdx.x * 64;
    int w = t >> 6, lane = t & 63;
    int q = lane >> 4, lm = lane & 15;

    f32x4 acc[8];
#pragma unroll
    for (int ct = 0; ct < 8; ++ct) acc[ct] = (f32x4){0.f, 0.f, 0.f, 0.f};

    for (int kc = 0; kc < 7; ++kc) {
        // stage G chunk: 64 rows x 64 k (512 uint4), read-once -> nt
#pragma unroll
        for (int i = 0; i < 2; ++i) {
            int lin = t + 256 * i;
            int row = lin >> 3, seg = lin & 7;
            u32x4 v = __builtin_nontemporal_load(
                (const u32x4*)(G + (size_t)(m0 + row) * KE + kc * 64 + seg * 8));
            *(u32x4*)&Gs[row][seg * 8] = v;
        }
        // stage Wt chunk: 128 rows x 64 k (1024 uint4)
#pragma unroll
        for (int i = 0; i < 4; ++i) {
            int lin = t + 256 * i;
            int row = lin >> 3, seg = lin & 7;
            *(uint4*)&Ws[row][seg * 8] =
                *(const uint4*)(Wt + (size_t)row * KE + kc * 64 + seg * 8);
        }
        __syncthreads();
#pragma unroll
        for (int kt = 0; kt < 2; ++kt) {
            bf16x8 a = *(const bf16x8*)&Gs[w * 16 + lm][kt * 32 + q * 8];
#pragma unroll
            for (int ct = 0; ct < 8; ++ct) {
                bf16x8 bf = *(const bf16x8*)&Ws[ct * 16 + lm][kt * 32 + q * 8];
                acc[ct] = __builtin_amdgcn_mfma_f32_16x16x32_bf16(a, bf, acc[ct], 0, 0, 0);
            }
        }
        __syncthreads();
    }

    float gc[8], bc[8];
#pragma unroll
    for (int ct = 0; ct < 8; ++ct) {
        int col = ct * 16 + lm;
        gc[ct] = lng[col]; bc[ct] = lnb[col];
    }
#pragma unroll
    for (int reg = 0; reg < 4; ++reg) {
        size_t row = (size_t)m0 + w * 16 + q * 4 + reg;
        float xv[8];
        float s1 = 0.f, s2 = 0.f;
#pragma unroll
        for (int ct = 0; ct < 8; ++ct) {
            int col = ct * 16 + lm;
            float h = bf2f(HB[row * DM + col]);
            float v = h + fmaxf(acc[ct][reg], 0.f);
            xv[ct] = v; s1 += v; s2 += v * v;
        }
#pragma unroll
        for (int m = 1; m <= 8; m <<= 1) {
            s1 += __shfl_xor(s1, m, 64);
            s2 += __shfl_xor(s2, m, 64);
        }
        float mu  = s1 * (1.f / 128.f);
        float var = s2 * (1.f / 128.f) - mu * mu;
        float inv = rsqrtf(var + LN_EPS);
        if (write_f32) {
#pragma unroll
            for (int ct = 0; ct < 8; ++ct) {
                int col = ct * 16 + lm;
                out[row * DM + col] = (xv[ct] - mu) * inv * gc[ct] + bc[ct];
            }
        } else {
#pragma unroll
            for (int ct = 0; ct < 8; ++ct) {
                int col = ct * 16 + lm;
                HB[row * DM + col] = f2bf((xv[ct] - mu) * inv * gc[ct] + bc[ct]);
            }
        }
    }
}

extern "C" void kernel_launch(void* const* d_in, const int* in_sizes, int n_in,
                              void* d_out, int out_size, void* d_ws, size_t ws_size,
                              hipStream_t stream) {
    const float* node_feat = (const float*)d_in[0];
    const float* in_W   = (const float*)d_in[1];
    const float* in_b   = (const float*)d_in[2];
    const float* node_W = (const float*)d_in[3];   // [2][3][128][128]
    const float* node_b = (const float*)d_in[4];   // [2][3][128]
    const float* edge_W = (const float*)d_in[5];   // [2][2][16][128]
    const float* edge_b = (const float*)d_in[6];   // [2][2][128]
    const float* ln_g   = (const float*)d_in[7];   // [2][128]
    const float* ln_b   = (const float*)d_in[8];   // [2][128]
    const float* ea0    = (const float*)d_in[9];
    const float* ea1    = (const float*)d_in[10];
    const int*   ei0    = (const int*)d_in[11];
    const int*   ei1    = (const int*)d_in[12];
    const int*   ei2    = (const int*)d_in[13];
    float* out = (float*)d_out;

    char* ws = (char*)d_ws;
    size_t off = 0;
    auto alloc = [&](size_t bytes) -> void* {
        void* p = ws + off;
        off = (off + bytes + 255) & ~(size_t)255;
        return p;
    };
    unsigned short* HB     = (unsigned short*)alloc((size_t)BROWS * DM * 2);   // 20.5 MB
    unsigned short* G      = (unsigned short*)alloc((size_t)BROWS * KE * 2);   // 71.7 MB
    int*            cursor = (int*)alloc((size_t)3 * NNODES * 4);              // zeroed
    float*          S      = (float*)alloc((size_t)2 * NNODES * 16 * 4);
    int*            srcs   = (int*)alloc((size_t)3 * NNODES * CAP * 4);        // 15.4 MB
    int*            eids   = (int*)alloc((size_t)2 * NNODES * CAP * 4);        // 10.2 MB
    unsigned short* Wt     = (unsigned short*)alloc((size_t)2 * 128 * KE * 2);
    unsigned short* Wp     = (unsigned short*)alloc((size_t)128 * 64 * 2);

    hipMemsetAsync(cursor, 0, (size_t)3 * NNODES * 4, stream);

    k_scatter<<<(3 * NE + 255) / 256, 256, 0, stream>>>(ei0, ei1, ei2, cursor, srcs, eids);
    k_sgather<<<(2 * NNODES) / 4, 256, 0, stream>>>(cursor, eids, ea0, ea1, S);
    k_wprep<<<480, 256, 0, stream>>>(node_W, node_b, edge_W, edge_b, in_W, Wt, Wp);
    k_proj<<<BROWS / 64, 256, 0, stream>>>(node_feat, Wp, in_b, HB);

    for (int l = 0; l < 2; ++l) {
        k_spmm<<<10000, 256, 0, stream>>>(HB, cursor, srcs, S, G);
        k_gemm_ln<<<BROWS / 64, 256, 0, stream>>>(G, Wt + (size_t)l * 128 * KE, HB,
                                                  ln_g + (size_t)l * DM, ln_b + (size_t)l * DM,
                                                  out, l == 1);
    }
}

// Round 4
// 399.895 us; speedup vs baseline: 1.1215x; 1.1215x over previous
//
#include <hip/hip_runtime.h>

// MultiRelGraphTransformer on MI355X — round 10.
// vs r9: keep the (batch, col-half)->XCD split (PROVEN: FETCH 125->64MB, 2.56MB
// hot set L2-resides) but fix the lane geometry that caused the 2x regression:
// 8 lanes x dwordx4 (16B) per 128B half-row instead of 16 lanes x dwordx2 (8B).
// Restores r6's bytes-in-flight (64B/lane, 4KB/wave) and total gather instruction
// count while keeping L2 residency. 32 nodes/block (8-lane groups), 5000 blocks.
// Gather loop = r7's idx-prefetch form. nt stores on G, nt loads on srcs kept.

#define NNODES 20000
#define NB     4
#define BROWS  (NB * NNODES)   // 80000
#define DN     64
#define DM     128
#define NE     160000
#define CAP    64              // bucket capacity per (relation,dst); Poisson(8)
#define LN_EPS 1e-5f
#define KE     448             // 384 spmm cols + 64 ext cols
#define LDW    88              // LDS row stride in ushorts: 44 dw -> 2-way (free)

typedef __attribute__((ext_vector_type(8))) short bf16x8;
typedef __attribute__((ext_vector_type(4))) float f32x4;
typedef __attribute__((ext_vector_type(2))) float f32x2;
typedef __attribute__((ext_vector_type(8))) unsigned short u16x8;
typedef __attribute__((ext_vector_type(4))) int i32x4;
typedef __attribute__((ext_vector_type(4))) unsigned int u32x4;

__device__ inline float bf2f(unsigned short u) {
    union { unsigned int i; float f; } x; x.i = ((unsigned int)u) << 16; return x.f;
}
__device__ inline unsigned short f2bf(float f) {
    union { float f; unsigned int i; } x; x.f = f;
    unsigned int r = x.i + 0x7FFFu + ((x.i >> 16) & 1u);
    return (unsigned short)(r >> 16);
}
// unpack one dword (2 bf16) into a packed float2 {lo, hi}
__device__ inline f32x2 bfpair(unsigned int w) {
    union { unsigned int u; float f; } lo, hi;
    lo.u = w << 16; hi.u = w & 0xffff0000u;
    return (f32x2){lo.f, hi.f};
}

// ---------- K1: counting-sort into fixed buckets (cursor = true degree) ----------
// srcs[] stores BYTE offsets into an HB batch plane: src * DM * 2 = src*256.
__global__ void k_scatter(const int* __restrict__ ei0, const int* __restrict__ ei1,
                          const int* __restrict__ ei2, int* __restrict__ cursor,
                          int* __restrict__ srcs, int* __restrict__ eids) {
    int tid = blockIdx.x * blockDim.x + threadIdx.x;
    if (tid >= 3 * NE) return;
    int r = tid / NE, e = tid - r * NE;
    const int* ei = (r == 0) ? ei0 : ((r == 1) ? ei1 : ei2);
    int src = ei[e], dst = ei[NE + e];
    int p = atomicAdd(&cursor[r * NNODES + dst], 1);
    if (p < CAP) {
        srcs[(r * NNODES + dst) * CAP + p] = src << 8;   // byte offset
        if (r < 2) eids[(r * NNODES + dst) * CAP + p] = e;
    }
}

// ---------- K2: S[r][n][16] = sum of ea_r over incoming edges (bucket walk) ----------
__global__ __launch_bounds__(256) void k_sgather(const int* __restrict__ deg,
                                                 const int* __restrict__ eids,
                                                 const float* __restrict__ ea0,
                                                 const float* __restrict__ ea1,
                                                 float* __restrict__ S) {
    int task = blockIdx.x * 4 + (threadIdx.x >> 6);   // 0 .. 2*NNODES-1
    int r = task / NNODES;
    const float* ea = r ? ea1 : ea0;
    int lane = threadIdx.x & 63;
    int k = lane & 15, sub = lane >> 4;
    int dg = deg[task]; if (dg > CAP) dg = CAP;
    const int* bk = eids + (size_t)task * CAP;
    float acc = 0.f;
    for (int j = sub; j < dg; j += 4) {
        int e = bk[j];
        acc += ea[e * 16 + k];
    }
    acc += __shfl_xor(acc, 16, 64);
    acc += __shfl_xor(acc, 32, 64);
    if (lane < 16) S[(size_t)task * 16 + k] = acc;
}

// ---------- K3: build Wt[2][128][448] (transposed node_W + ext rows) and Wp[128][64] ----------
__global__ __launch_bounds__(256) void k_wprep(const float* __restrict__ nW,
                                               const float* __restrict__ nb,
                                               const float* __restrict__ eW,
                                               const float* __restrict__ eb,
                                               const float* __restrict__ inW,
                                               unsigned short* __restrict__ Wt,
                                               unsigned short* __restrict__ Wp) {
    int lin = blockIdx.x * 256 + threadIdx.x;    // 2*128*448 + 128*64 = 122880
    if (lin < 2 * 128 * KE) {
        int l = lin / (128 * KE);
        int rem = lin - l * 128 * KE;
        int n = rem / KE, k = rem - n * KE;
        float v;
        if (k < 384) {
            int r = k >> 7, kk = k & 127;
            v = nW[(((size_t)(l * 3 + r) * 128) + kk) * 128 + n];
        } else {
            int e = k - 384;
            if (e < 3) {
                v = nb[(l * 3 + e) * DM + n];
                if (e < 2) v += eb[(l * 2 + e) * DM + n];
            } else if (e < 35) {
                int r2 = (e - 3) >> 4, j = (e - 3) & 15;
                v = eW[((size_t)((l * 2 + r2) * 16 + j)) * DM + n];
            } else v = 0.f;
        }
        Wt[lin] = f2bf(v);
    } else {
        int i = lin - 2 * 128 * KE;
        int n = i >> 6, k = i & 63;
        Wp[n * 64 + k] = f2bf(inW[(size_t)k * DM + n]);
    }
}

// ---------- K4: input projection HB = bf16(node_feat @ in_W + in_b), MFMA ----------
__global__ __launch_bounds__(256) void k_proj(const float* __restrict__ X,
                                              const unsigned short* __restrict__ Wp,  // [128][64]
                                              const float* __restrict__ bias,
                                              unsigned short* __restrict__ HB) {
    __shared__ __align__(16) unsigned short As[64][LDW];
    __shared__ __align__(16) unsigned short Bs[128][LDW];
    int t = threadIdx.x;
    int m0 = blockIdx.x * 64;
#pragma unroll
    for (int i = 0; i < 4; ++i) {
        int lin = t + 256 * i;                 // 0..1023 (64 rows x 16 float4-segs)
        int row = lin >> 4, seg = lin & 15;
        float4 v = *(const float4*)(X + (size_t)(m0 + row) * DN + seg * 4);
        ushort4 h; h.x = f2bf(v.x); h.y = f2bf(v.y); h.z = f2bf(v.z); h.w = f2bf(v.w);
        *(ushort4*)&As[row][seg * 4] = h;
    }
#pragma unroll
    for (int i = 0; i < 4; ++i) {
        int lin = t + 256 * i;                 // 0..1023 (128 rows x 8 uint4-segs)
        int row = lin >> 3, seg = lin & 7;
        *(uint4*)&Bs[row][seg * 8] = *(const uint4*)(Wp + (size_t)row * 64 + seg * 8);
    }
    __syncthreads();
    int w = t >> 6, lane = t & 63;
    int q = lane >> 4, lm = lane & 15;
    f32x4 acc[8];
#pragma unroll
    for (int ct = 0; ct < 8; ++ct) acc[ct] = (f32x4){0.f, 0.f, 0.f, 0.f};
#pragma unroll
    for (int kt = 0; kt < 2; ++kt) {
        bf16x8 a = *(const bf16x8*)&As[w * 16 + lm][kt * 32 + q * 8];
#pragma unroll
        for (int ct = 0; ct < 8; ++ct) {
            bf16x8 bf = *(const bf16x8*)&Bs[ct * 16 + lm][kt * 32 + q * 8];
            acc[ct] = __builtin_amdgcn_mfma_f32_16x16x32_bf16(a, bf, acc[ct], 0, 0, 0);
        }
    }
#pragma unroll
    for (int reg = 0; reg < 4; ++reg) {
        int row = m0 + w * 16 + q * 4 + reg;
#pragma unroll
        for (int ct = 0; ct < 8; ++ct) {
            int col = ct * 16 + lm;
            HB[(size_t)row * DM + col] = f2bf(acc[ct][reg] + bias[col]);
        }
    }
}

__device__ inline void acc4(f32x2* a, uint4 p0, uint4 p1, uint4 p2, uint4 p3) {
    a[0] += (bfpair(p0.x) + bfpair(p1.x)) + (bfpair(p2.x) + bfpair(p3.x));
    a[1] += (bfpair(p0.y) + bfpair(p1.y)) + (bfpair(p2.y) + bfpair(p3.y));
    a[2] += (bfpair(p0.z) + bfpair(p1.z)) + (bfpair(p2.z) + bfpair(p3.z));
    a[3] += (bfpair(p0.w) + bfpair(p1.w)) + (bfpair(p2.w) + bfpair(p3.w));
}

// ---------- gather one relation, one column half: 16B/lane (8 lanes/row), idx-pipelined ----------
__device__ inline void gather_rel16(const char* __restrict__ HbB2, unsigned c16,
                                    const int* __restrict__ bk, int dg, f32x2* a) {
#pragma unroll
    for (int i = 0; i < 4; ++i) a[i] = (f32x2){0.f, 0.f};
    int j = 0;
    if (dg >= 4) {
        i32x4 s4 = __builtin_nontemporal_load((const i32x4*)bk);
        while (j + 3 < dg) {
            i32x4 nxt = s4;
            if (j + 7 < dg) nxt = __builtin_nontemporal_load((const i32x4*)(bk + j + 4));
            uint4 u0 = *(const uint4*)(HbB2 + ((unsigned)s4.x + c16));
            uint4 u1 = *(const uint4*)(HbB2 + ((unsigned)s4.y + c16));
            uint4 u2 = *(const uint4*)(HbB2 + ((unsigned)s4.z + c16));
            uint4 u3 = *(const uint4*)(HbB2 + ((unsigned)s4.w + c16));
            acc4(a, u0, u1, u2, u3);
            j += 4;
            s4 = nxt;
        }
    }
    for (; j < dg; ++j) {
        uint4 u = *(const uint4*)(HbB2 + ((unsigned)bk[j] + c16));
        a[0] += bfpair(u.x); a[1] += bfpair(u.y);
        a[2] += bfpair(u.z); a[3] += bfpair(u.w);
    }
}

// ---------- K5: SpMM + ext-col write, (batch, col-half) per XCD ----------
// Block = 32 nodes x one (batch bb, half hh); 8 lanes x dwordx4 per half-row.
// Hot gather set per XCD = 20000 x 128B = 2.56MB -> fits 4MB L2.
__global__ __launch_bounds__(256) void k_spmm(const unsigned short* __restrict__ HB,
                                              const int* __restrict__ deg,
                                              const int* __restrict__ srcs,
                                              const float* __restrict__ S,
                                              unsigned short* __restrict__ G) {
    int blk = blockIdx.x;                      // 5000
    int s = blk & 7;                           // XCD id (round-robin dispatch)
    int bb = s >> 1;                           // batch
    int hh = s & 1;                            // column half
    int idx = blk >> 3;                        // [0,625)
    int t = threadIdx.x;
    int g = t >> 3, lane8 = t & 7;             // 32 nodes/block, 8 lanes/node
    int n = idx * 32 + g;
    unsigned c16 = (unsigned)lane8 * 16;       // byte offset within 128B half-row
    const char* HbB2 = (const char*)HB + (size_t)bb * NNODES * DM * 2 + hh * 128;
    size_t rowbase = ((size_t)(bb * NNODES + n)) * KE;

    int dt0 = deg[n], dt1 = deg[NNODES + n], dt2 = deg[2 * NNODES + n];
    const int* bk0 = srcs + (size_t)n * CAP;
    const int* bk1 = bk0 + (size_t)NNODES * CAP;
    const int* bk2 = bk1 + (size_t)NNODES * CAP;

    f32x2 a[4];
    u16x8 o;

    gather_rel16(HbB2, c16, bk0, dt0 > CAP ? CAP : dt0, a);
#pragma unroll
    for (int i = 0; i < 4; ++i) { o[2 * i] = f2bf(a[i].x); o[2 * i + 1] = f2bf(a[i].y); }
    __builtin_nontemporal_store(o, (u16x8*)(G + rowbase + 0 * 128 + hh * 64 + lane8 * 8));

    gather_rel16(HbB2, c16, bk1, dt1 > CAP ? CAP : dt1, a);
#pragma unroll
    for (int i = 0; i < 4; ++i) { o[2 * i] = f2bf(a[i].x); o[2 * i + 1] = f2bf(a[i].y); }
    __builtin_nontemporal_store(o, (u16x8*)(G + rowbase + 1 * 128 + hh * 64 + lane8 * 8));

    gather_rel16(HbB2, c16, bk2, dt2 > CAP ? CAP : dt2, a);
#pragma unroll
    for (int i = 0; i < 4; ++i) { o[2 * i] = f2bf(a[i].x); o[2 * i + 1] = f2bf(a[i].y); }
    __builtin_nontemporal_store(o, (u16x8*)(G + rowbase + 2 * 128 + hh * 64 + lane8 * 8));

    // ext cols: written once (half 0); all 8 lanes write 8 bf16 each -> kk = lane8*8+j
    if (hh == 0) {
        int dt[3] = {dt0, dt1, dt2};
        u16x8 e;
#pragma unroll
        for (int j = 0; j < 8; ++j) {
            int kk = lane8 * 8 + j;
            float v;
            if (kk < 3)       v = (float)dt[kk];
            else if (kk < 19) v = S[((size_t)(0 * NNODES + n)) * 16 + (kk - 3)];
            else if (kk < 35) v = S[((size_t)(1 * NNODES + n)) * 16 + (kk - 19)];
            else              v = 0.f;
            e[j] = f2bf(v);
        }
        __builtin_nontemporal_store(e, (u16x8*)(G + rowbase + 384 + lane8 * 8));
    }
}

// ---------- K6: bf16 MFMA GEMM [64x448]@[448x128] + residual + ReLU + LN ----------
// (r6 shape: 64-row M-tile, 4 blocks/CU, 1250 blocks; nt loads on read-once G)
__global__ __launch_bounds__(256) void k_gemm_ln(const unsigned short* __restrict__ G,   // [BROWS][448]
                                                 const unsigned short* __restrict__ Wt,  // [128][448]
                                                 unsigned short* HB,
                                                 const float* __restrict__ lng,
                                                 const float* __restrict__ lnb,
                                                 float* __restrict__ out, int write_f32) {
    __shared__ __align__(16) unsigned short Gs[64][LDW];
    __shared__ __align__(16) unsigned short Ws[128][LDW];
    int t = threadIdx.x;
    int m0 = blockIdx.x * 64;
    int w = t >> 6, lane = t & 63;
    int q = lane >> 4, lm = lane & 15;

    f32x4 acc[8];
#pragma unroll
    for (int ct = 0; ct < 8; ++ct) acc[ct] = (f32x4){0.f, 0.f, 0.f, 0.f};

    for (int kc = 0; kc < 7; ++kc) {
        // stage G chunk: 64 rows x 64 k (512 uint4), read-once -> nt
#pragma unroll
        for (int i = 0; i < 2; ++i) {
            int lin = t + 256 * i;
            int row = lin >> 3, seg = lin & 7;
            u32x4 v = __builtin_nontemporal_load(
                (const u32x4*)(G + (size_t)(m0 + row) * KE + kc * 64 + seg * 8));
            *(u32x4*)&Gs[row][seg * 8] = v;
        }
        // stage Wt chunk: 128 rows x 64 k (1024 uint4)
#pragma unroll
        for (int i = 0; i < 4; ++i) {
            int lin = t + 256 * i;
            int row = lin >> 3, seg = lin & 7;
            *(uint4*)&Ws[row][seg * 8] =
                *(const uint4*)(Wt + (size_t)row * KE + kc * 64 + seg * 8);
        }
        __syncthreads();
#pragma unroll
        for (int kt = 0; kt < 2; ++kt) {
            bf16x8 a = *(const bf16x8*)&Gs[w * 16 + lm][kt * 32 + q * 8];
#pragma unroll
            for (int ct = 0; ct < 8; ++ct) {
                bf16x8 bf = *(const bf16x8*)&Ws[ct * 16 + lm][kt * 32 + q * 8];
                acc[ct] = __builtin_amdgcn_mfma_f32_16x16x32_bf16(a, bf, acc[ct], 0, 0, 0);
            }
        }
        __syncthreads();
    }

    float gc[8], bc[8];
#pragma unroll
    for (int ct = 0; ct < 8; ++ct) {
        int col = ct * 16 + lm;
        gc[ct] = lng[col]; bc[ct] = lnb[col];
    }
#pragma unroll
    for (int reg = 0; reg < 4; ++reg) {
        size_t row = (size_t)m0 + w * 16 + q * 4 + reg;
        float xv[8];
        float s1 = 0.f, s2 = 0.f;
#pragma unroll
        for (int ct = 0; ct < 8; ++ct) {
            int col = ct * 16 + lm;
            float h = bf2f(HB[row * DM + col]);
            float v = h + fmaxf(acc[ct][reg], 0.f);
            xv[ct] = v; s1 += v; s2 += v * v;
        }
#pragma unroll
        for (int m = 1; m <= 8; m <<= 1) {
            s1 += __shfl_xor(s1, m, 64);
            s2 += __shfl_xor(s2, m, 64);
        }
        float mu  = s1 * (1.f / 128.f);
        float var = s2 * (1.f / 128.f) - mu * mu;
        float inv = rsqrtf(var + LN_EPS);
        if (write_f32) {
#pragma unroll
            for (int ct = 0; ct < 8; ++ct) {
                int col = ct * 16 + lm;
                out[row * DM + col] = (xv[ct] - mu) * inv * gc[ct] + bc[ct];
            }
        } else {
#pragma unroll
            for (int ct = 0; ct < 8; ++ct) {
                int col = ct * 16 + lm;
                HB[row * DM + col] = f2bf((xv[ct] - mu) * inv * gc[ct] + bc[ct]);
            }
        }
    }
}

extern "C" void kernel_launch(void* const* d_in, const int* in_sizes, int n_in,
                              void* d_out, int out_size, void* d_ws, size_t ws_size,
                              hipStream_t stream) {
    const float* node_feat = (const float*)d_in[0];
    const float* in_W   = (const float*)d_in[1];
    const float* in_b   = (const float*)d_in[2];
    const float* node_W = (const float*)d_in[3];   // [2][3][128][128]
    const float* node_b = (const float*)d_in[4];   // [2][3][128]
    const float* edge_W = (const float*)d_in[5];   // [2][2][16][128]
    const float* edge_b = (const float*)d_in[6];   // [2][2][128]
    const float* ln_g   = (const float*)d_in[7];   // [2][128]
    const float* ln_b   = (const float*)d_in[8];   // [2][128]
    const float* ea0    = (const float*)d_in[9];
    const float* ea1    = (const float*)d_in[10];
    const int*   ei0    = (const int*)d_in[11];
    const int*   ei1    = (const int*)d_in[12];
    const int*   ei2    = (const int*)d_in[13];
    float* out = (float*)d_out;

    char* ws = (char*)d_ws;
    size_t off = 0;
    auto alloc = [&](size_t bytes) -> void* {
        void* p = ws + off;
        off = (off + bytes + 255) & ~(size_t)255;
        return p;
    };
    unsigned short* HB     = (unsigned short*)alloc((size_t)BROWS * DM * 2);   // 20.5 MB
    unsigned short* G      = (unsigned short*)alloc((size_t)BROWS * KE * 2);   // 71.7 MB
    int*            cursor = (int*)alloc((size_t)3 * NNODES * 4);              // zeroed
    float*          S      = (float*)alloc((size_t)2 * NNODES * 16 * 4);
    int*            srcs   = (int*)alloc((size_t)3 * NNODES * CAP * 4);        // 15.4 MB
    int*            eids   = (int*)alloc((size_t)2 * NNODES * CAP * 4);        // 10.2 MB
    unsigned short* Wt     = (unsigned short*)alloc((size_t)2 * 128 * KE * 2);
    unsigned short* Wp     = (unsigned short*)alloc((size_t)128 * 64 * 2);

    hipMemsetAsync(cursor, 0, (size_t)3 * NNODES * 4, stream);

    k_scatter<<<(3 * NE + 255) / 256, 256, 0, stream>>>(ei0, ei1, ei2, cursor, srcs, eids);
    k_sgather<<<(2 * NNODES) / 4, 256, 0, stream>>>(cursor, eids, ea0, ea1, S);
    k_wprep<<<480, 256, 0, stream>>>(node_W, node_b, edge_W, edge_b, in_W, Wt, Wp);
    k_proj<<<BROWS / 64, 256, 0, stream>>>(node_feat, Wp, in_b, HB);

    for (int l = 0; l < 2; ++l) {
        k_spmm<<<5000, 256, 0, stream>>>(HB, cursor, srcs, S, G);
        k_gemm_ln<<<BROWS / 64, 256, 0, stream>>>(G, Wt + (size_t)l * 128 * KE, HB,
                                                  ln_g + (size_t)l * DM, ln_b + (size_t)l * DM,
                                                  out, l == 1);
    }
}

// Round 5
// 333.191 us; speedup vs baseline: 1.3460x; 1.2002x over previous
//
#include <hip/hip_runtime.h>

// MultiRelGraphTransformer on MI355X — round 11.
// vs r10: ONE change — srcs index loads back to plain cached loads (r9 added
// nontemporal_load on them; that bypasses L2 allocate, so every bucket step
// paid ~900cy HBM latency at the HEAD of the gather dep chain; a 1-deep
// prefetch can't hide that). A 256B bucket now costs 1 miss + L1 hits.
// Keep: (batch,col-half)->XCD split (FETCH 125->71MB proven), 8-lane x 16B
// geometry (r10), nt stores on G (write-no-allocate protects hot HB in L2),
// nt load of G in k_gemm_ln.

#define NNODES 20000
#define NB     4
#define BROWS  (NB * NNODES)   // 80000
#define DN     64
#define DM     128
#define NE     160000
#define CAP    64              // bucket capacity per (relation,dst); Poisson(8)
#define LN_EPS 1e-5f
#define KE     448             // 384 spmm cols + 64 ext cols
#define LDW    88              // LDS row stride in ushorts: 44 dw -> 2-way (free)

typedef __attribute__((ext_vector_type(8))) short bf16x8;
typedef __attribute__((ext_vector_type(4))) float f32x4;
typedef __attribute__((ext_vector_type(2))) float f32x2;
typedef __attribute__((ext_vector_type(8))) unsigned short u16x8;
typedef __attribute__((ext_vector_type(4))) int i32x4;
typedef __attribute__((ext_vector_type(4))) unsigned int u32x4;

__device__ inline float bf2f(unsigned short u) {
    union { unsigned int i; float f; } x; x.i = ((unsigned int)u) << 16; return x.f;
}
__device__ inline unsigned short f2bf(float f) {
    union { float f; unsigned int i; } x; x.f = f;
    unsigned int r = x.i + 0x7FFFu + ((x.i >> 16) & 1u);
    return (unsigned short)(r >> 16);
}
// unpack one dword (2 bf16) into a packed float2 {lo, hi}
__device__ inline f32x2 bfpair(unsigned int w) {
    union { unsigned int u; float f; } lo, hi;
    lo.u = w << 16; hi.u = w & 0xffff0000u;
    return (f32x2){lo.f, hi.f};
}

// ---------- K1: counting-sort into fixed buckets (cursor = true degree) ----------
// srcs[] stores BYTE offsets into an HB batch plane: src * DM * 2 = src*256.
__global__ void k_scatter(const int* __restrict__ ei0, const int* __restrict__ ei1,
                          const int* __restrict__ ei2, int* __restrict__ cursor,
                          int* __restrict__ srcs, int* __restrict__ eids) {
    int tid = blockIdx.x * blockDim.x + threadIdx.x;
    if (tid >= 3 * NE) return;
    int r = tid / NE, e = tid - r * NE;
    const int* ei = (r == 0) ? ei0 : ((r == 1) ? ei1 : ei2);
    int src = ei[e], dst = ei[NE + e];
    int p = atomicAdd(&cursor[r * NNODES + dst], 1);
    if (p < CAP) {
        srcs[(r * NNODES + dst) * CAP + p] = src << 8;   // byte offset
        if (r < 2) eids[(r * NNODES + dst) * CAP + p] = e;
    }
}

// ---------- K2: S[r][n][16] = sum of ea_r over incoming edges (bucket walk) ----------
__global__ __launch_bounds__(256) void k_sgather(const int* __restrict__ deg,
                                                 const int* __restrict__ eids,
                                                 const float* __restrict__ ea0,
                                                 const float* __restrict__ ea1,
                                                 float* __restrict__ S) {
    int task = blockIdx.x * 4 + (threadIdx.x >> 6);   // 0 .. 2*NNODES-1
    int r = task / NNODES;
    const float* ea = r ? ea1 : ea0;
    int lane = threadIdx.x & 63;
    int k = lane & 15, sub = lane >> 4;
    int dg = deg[task]; if (dg > CAP) dg = CAP;
    const int* bk = eids + (size_t)task * CAP;
    float acc = 0.f;
    for (int j = sub; j < dg; j += 4) {
        int e = bk[j];
        acc += ea[e * 16 + k];
    }
    acc += __shfl_xor(acc, 16, 64);
    acc += __shfl_xor(acc, 32, 64);
    if (lane < 16) S[(size_t)task * 16 + k] = acc;
}

// ---------- K3: build Wt[2][128][448] (transposed node_W + ext rows) and Wp[128][64] ----------
__global__ __launch_bounds__(256) void k_wprep(const float* __restrict__ nW,
                                               const float* __restrict__ nb,
                                               const float* __restrict__ eW,
                                               const float* __restrict__ eb,
                                               const float* __restrict__ inW,
                                               unsigned short* __restrict__ Wt,
                                               unsigned short* __restrict__ Wp) {
    int lin = blockIdx.x * 256 + threadIdx.x;    // 2*128*448 + 128*64 = 122880
    if (lin < 2 * 128 * KE) {
        int l = lin / (128 * KE);
        int rem = lin - l * 128 * KE;
        int n = rem / KE, k = rem - n * KE;
        float v;
        if (k < 384) {
            int r = k >> 7, kk = k & 127;
            v = nW[(((size_t)(l * 3 + r) * 128) + kk) * 128 + n];
        } else {
            int e = k - 384;
            if (e < 3) {
                v = nb[(l * 3 + e) * DM + n];
                if (e < 2) v += eb[(l * 2 + e) * DM + n];
            } else if (e < 35) {
                int r2 = (e - 3) >> 4, j = (e - 3) & 15;
                v = eW[((size_t)((l * 2 + r2) * 16 + j)) * DM + n];
            } else v = 0.f;
        }
        Wt[lin] = f2bf(v);
    } else {
        int i = lin - 2 * 128 * KE;
        int n = i >> 6, k = i & 63;
        Wp[n * 64 + k] = f2bf(inW[(size_t)k * DM + n]);
    }
}

// ---------- K4: input projection HB = bf16(node_feat @ in_W + in_b), MFMA ----------
__global__ __launch_bounds__(256) void k_proj(const float* __restrict__ X,
                                              const unsigned short* __restrict__ Wp,  // [128][64]
                                              const float* __restrict__ bias,
                                              unsigned short* __restrict__ HB) {
    __shared__ __align__(16) unsigned short As[64][LDW];
    __shared__ __align__(16) unsigned short Bs[128][LDW];
    int t = threadIdx.x;
    int m0 = blockIdx.x * 64;
#pragma unroll
    for (int i = 0; i < 4; ++i) {
        int lin = t + 256 * i;                 // 0..1023 (64 rows x 16 float4-segs)
        int row = lin >> 4, seg = lin & 15;
        float4 v = *(const float4*)(X + (size_t)(m0 + row) * DN + seg * 4);
        ushort4 h; h.x = f2bf(v.x); h.y = f2bf(v.y); h.z = f2bf(v.z); h.w = f2bf(v.w);
        *(ushort4*)&As[row][seg * 4] = h;
    }
#pragma unroll
    for (int i = 0; i < 4; ++i) {
        int lin = t + 256 * i;                 // 0..1023 (128 rows x 8 uint4-segs)
        int row = lin >> 3, seg = lin & 7;
        *(uint4*)&Bs[row][seg * 8] = *(const uint4*)(Wp + (size_t)row * 64 + seg * 8);
    }
    __syncthreads();
    int w = t >> 6, lane = t & 63;
    int q = lane >> 4, lm = lane & 15;
    f32x4 acc[8];
#pragma unroll
    for (int ct = 0; ct < 8; ++ct) acc[ct] = (f32x4){0.f, 0.f, 0.f, 0.f};
#pragma unroll
    for (int kt = 0; kt < 2; ++kt) {
        bf16x8 a = *(const bf16x8*)&As[w * 16 + lm][kt * 32 + q * 8];
#pragma unroll
        for (int ct = 0; ct < 8; ++ct) {
            bf16x8 bf = *(const bf16x8*)&Bs[ct * 16 + lm][kt * 32 + q * 8];
            acc[ct] = __builtin_amdgcn_mfma_f32_16x16x32_bf16(a, bf, acc[ct], 0, 0, 0);
        }
    }
#pragma unroll
    for (int reg = 0; reg < 4; ++reg) {
        int row = m0 + w * 16 + q * 4 + reg;
#pragma unroll
        for (int ct = 0; ct < 8; ++ct) {
            int col = ct * 16 + lm;
            HB[(size_t)row * DM + col] = f2bf(acc[ct][reg] + bias[col]);
        }
    }
}

__device__ inline void acc4(f32x2* a, uint4 p0, uint4 p1, uint4 p2, uint4 p3) {
    a[0] += (bfpair(p0.x) + bfpair(p1.x)) + (bfpair(p2.x) + bfpair(p3.x));
    a[1] += (bfpair(p0.y) + bfpair(p1.y)) + (bfpair(p2.y) + bfpair(p3.y));
    a[2] += (bfpair(p0.z) + bfpair(p1.z)) + (bfpair(p2.z) + bfpair(p3.z));
    a[3] += (bfpair(p0.w) + bfpair(p1.w)) + (bfpair(p2.w) + bfpair(p3.w));
}

// ---------- gather one relation, one column half: 16B/lane (8 lanes/row), idx-pipelined ----------
__device__ inline void gather_rel16(const char* __restrict__ HbB2, unsigned c16,
                                    const int* __restrict__ bk, int dg, f32x2* a) {
#pragma unroll
    for (int i = 0; i < 4; ++i) a[i] = (f32x2){0.f, 0.f};
    int j = 0;
    if (dg >= 4) {
        i32x4 s4 = *(const i32x4*)bk;          // plain cached load (r11 revert)
        while (j + 3 < dg) {
            i32x4 nxt = s4;
            if (j + 7 < dg) nxt = *(const i32x4*)(bk + j + 4);
            uint4 u0 = *(const uint4*)(HbB2 + ((unsigned)s4.x + c16));
            uint4 u1 = *(const uint4*)(HbB2 + ((unsigned)s4.y + c16));
            uint4 u2 = *(const uint4*)(HbB2 + ((unsigned)s4.z + c16));
            uint4 u3 = *(const uint4*)(HbB2 + ((unsigned)s4.w + c16));
            acc4(a, u0, u1, u2, u3);
            j += 4;
            s4 = nxt;
        }
    }
    for (; j < dg; ++j) {
        uint4 u = *(const uint4*)(HbB2 + ((unsigned)bk[j] + c16));
        a[0] += bfpair(u.x); a[1] += bfpair(u.y);
        a[2] += bfpair(u.z); a[3] += bfpair(u.w);
    }
}

// ---------- K5: SpMM + ext-col write, (batch, col-half) per XCD ----------
// Block = 32 nodes x one (batch bb, half hh); 8 lanes x dwordx4 per half-row.
// Hot gather set per XCD = 20000 x 128B = 2.56MB -> fits 4MB L2.
__global__ __launch_bounds__(256) void k_spmm(const unsigned short* __restrict__ HB,
                                              const int* __restrict__ deg,
                                              const int* __restrict__ srcs,
                                              const float* __restrict__ S,
                                              unsigned short* __restrict__ G) {
    int blk = blockIdx.x;                      // 5000
    int s = blk & 7;                           // XCD id (round-robin dispatch)
    int bb = s >> 1;                           // batch
    int hh = s & 1;                            // column half
    int idx = blk >> 3;                        // [0,625)
    int t = threadIdx.x;
    int g = t >> 3, lane8 = t & 7;             // 32 nodes/block, 8 lanes/node
    int n = idx * 32 + g;
    unsigned c16 = (unsigned)lane8 * 16;       // byte offset within 128B half-row
    const char* HbB2 = (const char*)HB + (size_t)bb * NNODES * DM * 2 + hh * 128;
    size_t rowbase = ((size_t)(bb * NNODES + n)) * KE;

    int dt0 = deg[n], dt1 = deg[NNODES + n], dt2 = deg[2 * NNODES + n];
    const int* bk0 = srcs + (size_t)n * CAP;
    const int* bk1 = bk0 + (size_t)NNODES * CAP;
    const int* bk2 = bk1 + (size_t)NNODES * CAP;

    f32x2 a[4];
    u16x8 o;

    gather_rel16(HbB2, c16, bk0, dt0 > CAP ? CAP : dt0, a);
#pragma unroll
    for (int i = 0; i < 4; ++i) { o[2 * i] = f2bf(a[i].x); o[2 * i + 1] = f2bf(a[i].y); }
    __builtin_nontemporal_store(o, (u16x8*)(G + rowbase + 0 * 128 + hh * 64 + lane8 * 8));

    gather_rel16(HbB2, c16, bk1, dt1 > CAP ? CAP : dt1, a);
#pragma unroll
    for (int i = 0; i < 4; ++i) { o[2 * i] = f2bf(a[i].x); o[2 * i + 1] = f2bf(a[i].y); }
    __builtin_nontemporal_store(o, (u16x8*)(G + rowbase + 1 * 128 + hh * 64 + lane8 * 8));

    gather_rel16(HbB2, c16, bk2, dt2 > CAP ? CAP : dt2, a);
#pragma unroll
    for (int i = 0; i < 4; ++i) { o[2 * i] = f2bf(a[i].x); o[2 * i + 1] = f2bf(a[i].y); }
    __builtin_nontemporal_store(o, (u16x8*)(G + rowbase + 2 * 128 + hh * 64 + lane8 * 8));

    // ext cols: written once (half 0); all 8 lanes write 8 bf16 each -> kk = lane8*8+j
    if (hh == 0) {
        int dt[3] = {dt0, dt1, dt2};
        u16x8 e;
#pragma unroll
        for (int j = 0; j < 8; ++j) {
            int kk = lane8 * 8 + j;
            float v;
            if (kk < 3)       v = (float)dt[kk];
            else if (kk < 19) v = S[((size_t)(0 * NNODES + n)) * 16 + (kk - 3)];
            else if (kk < 35) v = S[((size_t)(1 * NNODES + n)) * 16 + (kk - 19)];
            else              v = 0.f;
            e[j] = f2bf(v);
        }
        __builtin_nontemporal_store(e, (u16x8*)(G + rowbase + 384 + lane8 * 8));
    }
}

// ---------- K6: bf16 MFMA GEMM [64x448]@[448x128] + residual + ReLU + LN ----------
// (r6 shape: 64-row M-tile, 4 blocks/CU, 1250 blocks; nt loads on read-once G)
__global__ __launch_bounds__(256) void k_gemm_ln(const unsigned short* __restrict__ G,   // [BROWS][448]
                                                 const unsigned short* __restrict__ Wt,  // [128][448]
                                                 unsigned short* HB,
                                                 const float* __restrict__ lng,
                                                 const float* __restrict__ lnb,
                                                 float* __restrict__ out, int write_f32) {
    __shared__ __align__(16) unsigned short Gs[64][LDW];
    __shared__ __align__(16) unsigned short Ws[128][LDW];
    int t = threadIdx.x;
    int m0 = blockIdx.x * 64;
    int w = t >> 6, lane = t & 63;
    int q = lane >> 4, lm = lane & 15;

    f32x4 acc[8];
#pragma unroll
    for (int ct = 0; ct < 8; ++ct) acc[ct] = (f32x4){0.f, 0.f, 0.f, 0.f};

    for (int kc = 0; kc < 7; ++kc) {
        // stage G chunk: 64 rows x 64 k (512 uint4), read-once -> nt
#pragma unroll
        for (int i = 0; i < 2; ++i) {
            int lin = t + 256 * i;
            int row = lin >> 3, seg = lin & 7;
            u32x4 v = __builtin_nontemporal_load(
                (const u32x4*)(G + (size_t)(m0 + row) * KE + kc * 64 + seg * 8));
            *(u32x4*)&Gs[row][seg * 8] = v;
        }
        // stage Wt chunk: 128 rows x 64 k (1024 uint4)
#pragma unroll
        for (int i = 0; i < 4; ++i) {
            int lin = t + 256 * i;
            int row = lin >> 3, seg = lin & 7;
            *(uint4*)&Ws[row][seg * 8] =
                *(const uint4*)(Wt + (size_t)row * KE + kc * 64 + seg * 8);
        }
        __syncthreads();
#pragma unroll
        for (int kt = 0; kt < 2; ++kt) {
            bf16x8 a = *(const bf16x8*)&Gs[w * 16 + lm][kt * 32 + q * 8];
#pragma unroll
            for (int ct = 0; ct < 8; ++ct) {
                bf16x8 bf = *(const bf16x8*)&Ws[ct * 16 + lm][kt * 32 + q * 8];
                acc[ct] = __builtin_amdgcn_mfma_f32_16x16x32_bf16(a, bf, acc[ct], 0, 0, 0);
            }
        }
        __syncthreads();
    }

    float gc[8], bc[8];
#pragma unroll
    for (int ct = 0; ct < 8; ++ct) {
        int col = ct * 16 + lm;
        gc[ct] = lng[col]; bc[ct] = lnb[col];
    }
#pragma unroll
    for (int reg = 0; reg < 4; ++reg) {
        size_t row = (size_t)m0 + w * 16 + q * 4 + reg;
        float xv[8];
        float s1 = 0.f, s2 = 0.f;
#pragma unroll
        for (int ct = 0; ct < 8; ++ct) {
            int col = ct * 16 + lm;
            float h = bf2f(HB[row * DM + col]);
            float v = h + fmaxf(acc[ct][reg], 0.f);
            xv[ct] = v; s1 += v; s2 += v * v;
        }
#pragma unroll
        for (int m = 1; m <= 8; m <<= 1) {
            s1 += __shfl_xor(s1, m, 64);
            s2 += __shfl_xor(s2, m, 64);
        }
        float mu  = s1 * (1.f / 128.f);
        float var = s2 * (1.f / 128.f) - mu * mu;
        float inv = rsqrtf(var + LN_EPS);
        if (write_f32) {
#pragma unroll
            for (int ct = 0; ct < 8; ++ct) {
                int col = ct * 16 + lm;
                out[row * DM + col] = (xv[ct] - mu) * inv * gc[ct] + bc[ct];
            }
        } else {
#pragma unroll
            for (int ct = 0; ct < 8; ++ct) {
                int col = ct * 16 + lm;
                HB[row * DM + col] = f2bf((xv[ct] - mu) * inv * gc[ct] + bc[ct]);
            }
        }
    }
}

extern "C" void kernel_launch(void* const* d_in, const int* in_sizes, int n_in,
                              void* d_out, int out_size, void* d_ws, size_t ws_size,
                              hipStream_t stream) {
    const float* node_feat = (const float*)d_in[0];
    const float* in_W   = (const float*)d_in[1];
    const float* in_b   = (const float*)d_in[2];
    const float* node_W = (const float*)d_in[3];   // [2][3][128][128]
    const float* node_b = (const float*)d_in[4];   // [2][3][128]
    const float* edge_W = (const float*)d_in[5];   // [2][2][16][128]
    const float* edge_b = (const float*)d_in[6];   // [2][2][128]
    const float* ln_g   = (const float*)d_in[7];   // [2][128]
    const float* ln_b   = (const float*)d_in[8];   // [2][128]
    const float* ea0    = (const float*)d_in[9];
    const float* ea1    = (const float*)d_in[10];
    const int*   ei0    = (const int*)d_in[11];
    const int*   ei1    = (const int*)d_in[12];
    const int*   ei2    = (const int*)d_in[13];
    float* out = (float*)d_out;

    char* ws = (char*)d_ws;
    size_t off = 0;
    auto alloc = [&](size_t bytes) -> void* {
        void* p = ws + off;
        off = (off + bytes + 255) & ~(size_t)255;
        return p;
    };
    unsigned short* HB     = (unsigned short*)alloc((size_t)BROWS * DM * 2);   // 20.5 MB
    unsigned short* G      = (unsigned short*)alloc((size_t)BROWS * KE * 2);   // 71.7 MB
    int*            cursor = (int*)alloc((size_t)3 * NNODES * 4);              // zeroed
    float*          S      = (float*)alloc((size_t)2 * NNODES * 16 * 4);
    int*            srcs   = (int*)alloc((size_t)3 * NNODES * CAP * 4);        // 15.4 MB
    int*            eids   = (int*)alloc((size_t)2 * NNODES * CAP * 4);        // 10.2 MB
    unsigned short* Wt     = (unsigned short*)alloc((size_t)2 * 128 * KE * 2);
    unsigned short* Wp     = (unsigned short*)alloc((size_t)128 * 64 * 2);

    hipMemsetAsync(cursor, 0, (size_t)3 * NNODES * 4, stream);

    k_scatter<<<(3 * NE + 255) / 256, 256, 0, stream>>>(ei0, ei1, ei2, cursor, srcs, eids);
    k_sgather<<<(2 * NNODES) / 4, 256, 0, stream>>>(cursor, eids, ea0, ea1, S);
    k_wprep<<<480, 256, 0, stream>>>(node_W, node_b, edge_W, edge_b, in_W, Wt, Wp);
    k_proj<<<BROWS / 64, 256, 0, stream>>>(node_feat, Wp, in_b, HB);

    for (int l = 0; l < 2; ++l) {
        k_spmm<<<5000, 256, 0, stream>>>(HB, cursor, srcs, S, G);
        k_gemm_ln<<<BROWS / 64, 256, 0, stream>>>(G, Wt + (size_t)l * 128 * KE, HB,
                                                  ln_g + (size_t)l * DM, ln_b + (size_t)l * DM,
                                                  out, l == 1);
    }
}

// Round 6
// 332.399 us; speedup vs baseline: 1.3492x; 1.0024x over previous
//
#include <hip/hip_runtime.h>

// MultiRelGraphTransformer on MI355X — round 12.
// vs r11: ONE change — burst gather loads issued via inline-asm
// `global_load_dwordx4 ... off sc0` (agent scope: BYPASS L1, keep L2).
// Rationale: gather time is ~invariant (55-62µs) across L2 regimes and matches
// 30.7M lane-addrs at ~1/cy/CU; every gather misses L1 (2.56MB hot set vs 32KB,
// ~1% hit) so the L1 miss path is the suspected serial resource. sc0 routes
// requests straight to the (now-resident) L2. Serial tail keeps plain cached
// loads for compiler overlap. Everything else identical to r11.

#define NNODES 20000
#define NB     4
#define BROWS  (NB * NNODES)   // 80000
#define DN     64
#define DM     128
#define NE     160000
#define CAP    64              // bucket capacity per (relation,dst); Poisson(8)
#define LN_EPS 1e-5f
#define KE     448             // 384 spmm cols + 64 ext cols
#define LDW    88              // LDS row stride in ushorts: 44 dw -> 2-way (free)

typedef __attribute__((ext_vector_type(8))) short bf16x8;
typedef __attribute__((ext_vector_type(4))) float f32x4;
typedef __attribute__((ext_vector_type(2))) float f32x2;
typedef __attribute__((ext_vector_type(8))) unsigned short u16x8;
typedef __attribute__((ext_vector_type(4))) int i32x4;
typedef __attribute__((ext_vector_type(4))) unsigned int u32x4;

__device__ inline float bf2f(unsigned short u) {
    union { unsigned int i; float f; } x; x.i = ((unsigned int)u) << 16; return x.f;
}
__device__ inline unsigned short f2bf(float f) {
    union { float f; unsigned int i; } x; x.f = f;
    unsigned int r = x.i + 0x7FFFu + ((x.i >> 16) & 1u);
    return (unsigned short)(r >> 16);
}
// unpack one dword (2 bf16) into a packed float2 {lo, hi}
__device__ inline f32x2 bfpair(unsigned int w) {
    union { unsigned int u; float f; } lo, hi;
    lo.u = w << 16; hi.u = w & 0xffff0000u;
    return (f32x2){lo.f, hi.f};
}

// ---------- K1: counting-sort into fixed buckets (cursor = true degree) ----------
// srcs[] stores BYTE offsets into an HB batch plane: src * DM * 2 = src*256.
__global__ void k_scatter(const int* __restrict__ ei0, const int* __restrict__ ei1,
                          const int* __restrict__ ei2, int* __restrict__ cursor,
                          int* __restrict__ srcs, int* __restrict__ eids) {
    int tid = blockIdx.x * blockDim.x + threadIdx.x;
    if (tid >= 3 * NE) return;
    int r = tid / NE, e = tid - r * NE;
    const int* ei = (r == 0) ? ei0 : ((r == 1) ? ei1 : ei2);
    int src = ei[e], dst = ei[NE + e];
    int p = atomicAdd(&cursor[r * NNODES + dst], 1);
    if (p < CAP) {
        srcs[(r * NNODES + dst) * CAP + p] = src << 8;   // byte offset
        if (r < 2) eids[(r * NNODES + dst) * CAP + p] = e;
    }
}

// ---------- K2: S[r][n][16] = sum of ea_r over incoming edges (bucket walk) ----------
__global__ __launch_bounds__(256) void k_sgather(const int* __restrict__ deg,
                                                 const int* __restrict__ eids,
                                                 const float* __restrict__ ea0,
                                                 const float* __restrict__ ea1,
                                                 float* __restrict__ S) {
    int task = blockIdx.x * 4 + (threadIdx.x >> 6);   // 0 .. 2*NNODES-1
    int r = task / NNODES;
    const float* ea = r ? ea1 : ea0;
    int lane = threadIdx.x & 63;
    int k = lane & 15, sub = lane >> 4;
    int dg = deg[task]; if (dg > CAP) dg = CAP;
    const int* bk = eids + (size_t)task * CAP;
    float acc = 0.f;
    for (int j = sub; j < dg; j += 4) {
        int e = bk[j];
        acc += ea[e * 16 + k];
    }
    acc += __shfl_xor(acc, 16, 64);
    acc += __shfl_xor(acc, 32, 64);
    if (lane < 16) S[(size_t)task * 16 + k] = acc;
}

// ---------- K3: build Wt[2][128][448] (transposed node_W + ext rows) and Wp[128][64] ----------
__global__ __launch_bounds__(256) void k_wprep(const float* __restrict__ nW,
                                               const float* __restrict__ nb,
                                               const float* __restrict__ eW,
                                               const float* __restrict__ eb,
                                               const float* __restrict__ inW,
                                               unsigned short* __restrict__ Wt,
                                               unsigned short* __restrict__ Wp) {
    int lin = blockIdx.x * 256 + threadIdx.x;    // 2*128*448 + 128*64 = 122880
    if (lin < 2 * 128 * KE) {
        int l = lin / (128 * KE);
        int rem = lin - l * 128 * KE;
        int n = rem / KE, k = rem - n * KE;
        float v;
        if (k < 384) {
            int r = k >> 7, kk = k & 127;
            v = nW[(((size_t)(l * 3 + r) * 128) + kk) * 128 + n];
        } else {
            int e = k - 384;
            if (e < 3) {
                v = nb[(l * 3 + e) * DM + n];
                if (e < 2) v += eb[(l * 2 + e) * DM + n];
            } else if (e < 35) {
                int r2 = (e - 3) >> 4, j = (e - 3) & 15;
                v = eW[((size_t)((l * 2 + r2) * 16 + j)) * DM + n];
            } else v = 0.f;
        }
        Wt[lin] = f2bf(v);
    } else {
        int i = lin - 2 * 128 * KE;
        int n = i >> 6, k = i & 63;
        Wp[n * 64 + k] = f2bf(inW[(size_t)k * DM + n]);
    }
}

// ---------- K4: input projection HB = bf16(node_feat @ in_W + in_b), MFMA ----------
__global__ __launch_bounds__(256) void k_proj(const float* __restrict__ X,
                                              const unsigned short* __restrict__ Wp,  // [128][64]
                                              const float* __restrict__ bias,
                                              unsigned short* __restrict__ HB) {
    __shared__ __align__(16) unsigned short As[64][LDW];
    __shared__ __align__(16) unsigned short Bs[128][LDW];
    int t = threadIdx.x;
    int m0 = blockIdx.x * 64;
#pragma unroll
    for (int i = 0; i < 4; ++i) {
        int lin = t + 256 * i;                 // 0..1023 (64 rows x 16 float4-segs)
        int row = lin >> 4, seg = lin & 15;
        float4 v = *(const float4*)(X + (size_t)(m0 + row) * DN + seg * 4);
        ushort4 h; h.x = f2bf(v.x); h.y = f2bf(v.y); h.z = f2bf(v.z); h.w = f2bf(v.w);
        *(ushort4*)&As[row][seg * 4] = h;
    }
#pragma unroll
    for (int i = 0; i < 4; ++i) {
        int lin = t + 256 * i;                 // 0..1023 (128 rows x 8 uint4-segs)
        int row = lin >> 3, seg = lin & 7;
        *(uint4*)&Bs[row][seg * 8] = *(const uint4*)(Wp + (size_t)row * 64 + seg * 8);
    }
    __syncthreads();
    int w = t >> 6, lane = t & 63;
    int q = lane >> 4, lm = lane & 15;
    f32x4 acc[8];
#pragma unroll
    for (int ct = 0; ct < 8; ++ct) acc[ct] = (f32x4){0.f, 0.f, 0.f, 0.f};
#pragma unroll
    for (int kt = 0; kt < 2; ++kt) {
        bf16x8 a = *(const bf16x8*)&As[w * 16 + lm][kt * 32 + q * 8];
#pragma unroll
        for (int ct = 0; ct < 8; ++ct) {
            bf16x8 bf = *(const bf16x8*)&Bs[ct * 16 + lm][kt * 32 + q * 8];
            acc[ct] = __builtin_amdgcn_mfma_f32_16x16x32_bf16(a, bf, acc[ct], 0, 0, 0);
        }
    }
#pragma unroll
    for (int reg = 0; reg < 4; ++reg) {
        int row = m0 + w * 16 + q * 4 + reg;
#pragma unroll
        for (int ct = 0; ct < 8; ++ct) {
            int col = ct * 16 + lm;
            HB[(size_t)row * DM + col] = f2bf(acc[ct][reg] + bias[col]);
        }
    }
}

__device__ inline void acc4(f32x2* a, uint4 p0, uint4 p1, uint4 p2, uint4 p3) {
    a[0] += (bfpair(p0.x) + bfpair(p1.x)) + (bfpair(p2.x) + bfpair(p3.x));
    a[1] += (bfpair(p0.y) + bfpair(p1.y)) + (bfpair(p2.y) + bfpair(p3.y));
    a[2] += (bfpair(p0.z) + bfpair(p1.z)) + (bfpair(p2.z) + bfpair(p3.z));
    a[3] += (bfpair(p0.w) + bfpair(p1.w)) + (bfpair(p2.w) + bfpair(p3.w));
}

// ---------- gather one relation, one column half: 16B/lane (8 lanes/row) ----------
// Burst loads via inline asm with sc0 (bypass L1, keep/allocate L2).
__device__ inline void gather_rel16(const char* __restrict__ HbB2, unsigned c16,
                                    const int* __restrict__ bk, int dg, f32x2* a) {
#pragma unroll
    for (int i = 0; i < 4; ++i) a[i] = (f32x2){0.f, 0.f};
    int j = 0;
    if (dg >= 4) {
        i32x4 s4 = *(const i32x4*)bk;          // plain cached load (indices hot in L1)
        while (j + 3 < dg) {
            i32x4 nxt = s4;
            if (j + 7 < dg) nxt = *(const i32x4*)(bk + j + 4);
            const char* p0 = HbB2 + ((unsigned)s4.x + c16);
            const char* p1 = HbB2 + ((unsigned)s4.y + c16);
            const char* p2 = HbB2 + ((unsigned)s4.z + c16);
            const char* p3 = HbB2 + ((unsigned)s4.w + c16);
            uint4 u0, u1, u2, u3;
            asm volatile(
                "global_load_dwordx4 %0, %4, off sc0\n\t"
                "global_load_dwordx4 %1, %5, off sc0\n\t"
                "global_load_dwordx4 %2, %6, off sc0\n\t"
                "global_load_dwordx4 %3, %7, off sc0\n\t"
                "s_waitcnt vmcnt(0)"
                : "=&v"(u0), "=&v"(u1), "=&v"(u2), "=&v"(u3)
                : "v"(p0), "v"(p1), "v"(p2), "v"(p3));
            acc4(a, u0, u1, u2, u3);
            j += 4;
            s4 = nxt;
        }
    }
    for (; j < dg; ++j) {                      // tail: plain cached loads, compiler-overlapped
        uint4 u = *(const uint4*)(HbB2 + ((unsigned)bk[j] + c16));
        a[0] += bfpair(u.x); a[1] += bfpair(u.y);
        a[2] += bfpair(u.z); a[3] += bfpair(u.w);
    }
}

// ---------- K5: SpMM + ext-col write, (batch, col-half) per XCD ----------
// Block = 32 nodes x one (batch bb, half hh); 8 lanes x dwordx4 per half-row.
// Hot gather set per XCD = 20000 x 128B = 2.56MB -> fits 4MB L2.
__global__ __launch_bounds__(256) void k_spmm(const unsigned short* __restrict__ HB,
                                              const int* __restrict__ deg,
                                              const int* __restrict__ srcs,
                                              const float* __restrict__ S,
                                              unsigned short* __restrict__ G) {
    int blk = blockIdx.x;                      // 5000
    int s = blk & 7;                           // XCD id (round-robin dispatch)
    int bb = s >> 1;                           // batch
    int hh = s & 1;                            // column half
    int idx = blk >> 3;                        // [0,625)
    int t = threadIdx.x;
    int g = t >> 3, lane8 = t & 7;             // 32 nodes/block, 8 lanes/node
    int n = idx * 32 + g;
    unsigned c16 = (unsigned)lane8 * 16;       // byte offset within 128B half-row
    const char* HbB2 = (const char*)HB + (size_t)bb * NNODES * DM * 2 + hh * 128;
    size_t rowbase = ((size_t)(bb * NNODES + n)) * KE;

    int dt0 = deg[n], dt1 = deg[NNODES + n], dt2 = deg[2 * NNODES + n];
    const int* bk0 = srcs + (size_t)n * CAP;
    const int* bk1 = bk0 + (size_t)NNODES * CAP;
    const int* bk2 = bk1 + (size_t)NNODES * CAP;

    f32x2 a[4];
    u16x8 o;

    gather_rel16(HbB2, c16, bk0, dt0 > CAP ? CAP : dt0, a);
#pragma unroll
    for (int i = 0; i < 4; ++i) { o[2 * i] = f2bf(a[i].x); o[2 * i + 1] = f2bf(a[i].y); }
    __builtin_nontemporal_store(o, (u16x8*)(G + rowbase + 0 * 128 + hh * 64 + lane8 * 8));

    gather_rel16(HbB2, c16, bk1, dt1 > CAP ? CAP : dt1, a);
#pragma unroll
    for (int i = 0; i < 4; ++i) { o[2 * i] = f2bf(a[i].x); o[2 * i + 1] = f2bf(a[i].y); }
    __builtin_nontemporal_store(o, (u16x8*)(G + rowbase + 1 * 128 + hh * 64 + lane8 * 8));

    gather_rel16(HbB2, c16, bk2, dt2 > CAP ? CAP : dt2, a);
#pragma unroll
    for (int i = 0; i < 4; ++i) { o[2 * i] = f2bf(a[i].x); o[2 * i + 1] = f2bf(a[i].y); }
    __builtin_nontemporal_store(o, (u16x8*)(G + rowbase + 2 * 128 + hh * 64 + lane8 * 8));

    // ext cols: written once (half 0); all 8 lanes write 8 bf16 each -> kk = lane8*8+j
    if (hh == 0) {
        int dt[3] = {dt0, dt1, dt2};
        u16x8 e;
#pragma unroll
        for (int j = 0; j < 8; ++j) {
            int kk = lane8 * 8 + j;
            float v;
            if (kk < 3)       v = (float)dt[kk];
            else if (kk < 19) v = S[((size_t)(0 * NNODES + n)) * 16 + (kk - 3)];
            else if (kk < 35) v = S[((size_t)(1 * NNODES + n)) * 16 + (kk - 19)];
            else              v = 0.f;
            e[j] = f2bf(v);
        }
        __builtin_nontemporal_store(e, (u16x8*)(G + rowbase + 384 + lane8 * 8));
    }
}

// ---------- K6: bf16 MFMA GEMM [64x448]@[448x128] + residual + ReLU + LN ----------
// (r6 shape: 64-row M-tile, 4 blocks/CU, 1250 blocks; nt loads on read-once G)
__global__ __launch_bounds__(256) void k_gemm_ln(const unsigned short* __restrict__ G,   // [BROWS][448]
                                                 const unsigned short* __restrict__ Wt,  // [128][448]
                                                 unsigned short* HB,
                                                 const float* __restrict__ lng,
                                                 const float* __restrict__ lnb,
                                                 float* __restrict__ out, int write_f32) {
    __shared__ __align__(16) unsigned short Gs[64][LDW];
    __shared__ __align__(16) unsigned short Ws[128][LDW];
    int t = threadIdx.x;
    int m0 = blockIdx.x * 64;
    int w = t >> 6, lane = t & 63;
    int q = lane >> 4, lm = lane & 15;

    f32x4 acc[8];
#pragma unroll
    for (int ct = 0; ct < 8; ++ct) acc[ct] = (f32x4){0.f, 0.f, 0.f, 0.f};

    for (int kc = 0; kc < 7; ++kc) {
        // stage G chunk: 64 rows x 64 k (512 uint4), read-once -> nt
#pragma unroll
        for (int i = 0; i < 2; ++i) {
            int lin = t + 256 * i;
            int row = lin >> 3, seg = lin & 7;
            u32x4 v = __builtin_nontemporal_load(
                (const u32x4*)(G + (size_t)(m0 + row) * KE + kc * 64 + seg * 8));
            *(u32x4*)&Gs[row][seg * 8] = v;
        }
        // stage Wt chunk: 128 rows x 64 k (1024 uint4)
#pragma unroll
        for (int i = 0; i < 4; ++i) {
            int lin = t + 256 * i;
            int row = lin >> 3, seg = lin & 7;
            *(uint4*)&Ws[row][seg * 8] =
                *(const uint4*)(Wt + (size_t)row * KE + kc * 64 + seg * 8);
        }
        __syncthreads();
#pragma unroll
        for (int kt = 0; kt < 2; ++kt) {
            bf16x8 a = *(const bf16x8*)&Gs[w * 16 + lm][kt * 32 + q * 8];
#pragma unroll
            for (int ct = 0; ct < 8; ++ct) {
                bf16x8 bf = *(const bf16x8*)&Ws[ct * 16 + lm][kt * 32 + q * 8];
                acc[ct] = __builtin_amdgcn_mfma_f32_16x16x32_bf16(a, bf, acc[ct], 0, 0, 0);
            }
        }
        __syncthreads();
    }

    float gc[8], bc[8];
#pragma unroll
    for (int ct = 0; ct < 8; ++ct) {
        int col = ct * 16 + lm;
        gc[ct] = lng[col]; bc[ct] = lnb[col];
    }
#pragma unroll
    for (int reg = 0; reg < 4; ++reg) {
        size_t row = (size_t)m0 + w * 16 + q * 4 + reg;
        float xv[8];
        float s1 = 0.f, s2 = 0.f;
#pragma unroll
        for (int ct = 0; ct < 8; ++ct) {
            int col = ct * 16 + lm;
            float h = bf2f(HB[row * DM + col]);
            float v = h + fmaxf(acc[ct][reg], 0.f);
            xv[ct] = v; s1 += v; s2 += v * v;
        }
#pragma unroll
        for (int m = 1; m <= 8; m <<= 1) {
            s1 += __shfl_xor(s1, m, 64);
            s2 += __shfl_xor(s2, m, 64);
        }
        float mu  = s1 * (1.f / 128.f);
        float var = s2 * (1.f / 128.f) - mu * mu;
        float inv = rsqrtf(var + LN_EPS);
        if (write_f32) {
#pragma unroll
            for (int ct = 0; ct < 8; ++ct) {
                int col = ct * 16 + lm;
                out[row * DM + col] = (xv[ct] - mu) * inv * gc[ct] + bc[ct];
            }
        } else {
#pragma unroll
            for (int ct = 0; ct < 8; ++ct) {
                int col = ct * 16 + lm;
                HB[row * DM + col] = f2bf((xv[ct] - mu) * inv * gc[ct] + bc[ct]);
            }
        }
    }
}

extern "C" void kernel_launch(void* const* d_in, const int* in_sizes, int n_in,
                              void* d_out, int out_size, void* d_ws, size_t ws_size,
                              hipStream_t stream) {
    const float* node_feat = (const float*)d_in[0];
    const float* in_W   = (const float*)d_in[1];
    const float* in_b   = (const float*)d_in[2];
    const float* node_W = (const float*)d_in[3];   // [2][3][128][128]
    const float* node_b = (const float*)d_in[4];   // [2][3][128]
    const float* edge_W = (const float*)d_in[5];   // [2][2][16][128]
    const float* edge_b = (const float*)d_in[6];   // [2][2][128]
    const float* ln_g   = (const float*)d_in[7];   // [2][128]
    const float* ln_b   = (const float*)d_in[8];   // [2][128]
    const float* ea0    = (const float*)d_in[9];
    const float* ea1    = (const float*)d_in[10];
    const int*   ei0    = (const int*)d_in[11];
    const int*   ei1    = (const int*)d_in[12];
    const int*   ei2    = (const int*)d_in[13];
    float* out = (float*)d_out;

    char* ws = (char*)d_ws;
    size_t off = 0;
    auto alloc = [&](size_t bytes) -> void* {
        void* p = ws + off;
        off = (off + bytes + 255) & ~(size_t)255;
        return p;
    };
    unsigned short* HB     = (unsigned short*)alloc((size_t)BROWS * DM * 2);   // 20.5 MB
    unsigned short* G      = (unsigned short*)alloc((size_t)BROWS * KE * 2);   // 71.7 MB
    int*            cursor = (int*)alloc((size_t)3 * NNODES * 4);              // zeroed
    float*          S      = (float*)alloc((size_t)2 * NNODES * 16 * 4);
    int*            srcs   = (int*)alloc((size_t)3 * NNODES * CAP * 4);        // 15.4 MB
    int*            eids   = (int*)alloc((size_t)2 * NNODES * CAP * 4);        // 10.2 MB
    unsigned short* Wt     = (unsigned short*)alloc((size_t)2 * 128 * KE * 2);
    unsigned short* Wp     = (unsigned short*)alloc((size_t)128 * 64 * 2);

    hipMemsetAsync(cursor, 0, (size_t)3 * NNODES * 4, stream);

    k_scatter<<<(3 * NE + 255) / 256, 256, 0, stream>>>(ei0, ei1, ei2, cursor, srcs, eids);
    k_sgather<<<(2 * NNODES) / 4, 256, 0, stream>>>(cursor, eids, ea0, ea1, S);
    k_wprep<<<480, 256, 0, stream>>>(node_W, node_b, edge_W, edge_b, in_W, Wt, Wp);
    k_proj<<<BROWS / 64, 256, 0, stream>>>(node_feat, Wp, in_b, HB);

    for (int l = 0; l < 2; ++l) {
        k_spmm<<<5000, 256, 0, stream>>>(HB, cursor, srcs, S, G);
        k_gemm_ln<<<BROWS / 64, 256, 0, stream>>>(G, Wt + (size_t)l * 128 * KE, HB,
                                                  ln_g + (size_t)l * DM, ln_b + (size_t)l * DM,
                                                  out, l == 1);
    }
}